// Round 1
// baseline (427.351 us; speedup 1.0000x reference)
//
#include <hip/hip_runtime.h>

// out[m][n] = C[m][n] * D[n];  M = NR = 8192, fp32 in/out.
// Memory-bound broadcast multiply, ~537 MB total traffic -> roofline ~85 us @ 6.3 TB/s.
//
// Structure: persistent tiled grid (2048 blocks x 256 threads) instead of
// 65,536 one-shot blocks. Each thread owns ONE column-float4 (d loaded once,
// held in registers) and walks 32 rows at stride NR. #pragma unroll 8 keeps
// 8 independent loads in flight per thread. Nontemporal load/store: both
// streams are single-use and exceed the 256 MB LLC, so caching them is waste.

#define NR 8192
#define M_ROWS 8192
#define NC4 (NR / 4)              // 2048 float4 per row
#define ROWS_PER_THREAD 32
#define THREADS 256
// total threads = (M_ROWS / ROWS_PER_THREAD) * NC4 = 256 * 2048 = 524,288
#define BLOCKS (((M_ROWS / ROWS_PER_THREAD) * NC4) / THREADS)   // 2048

typedef float v4 __attribute__((ext_vector_type(4)));

__global__ __launch_bounds__(256) void colscale_kernel(
    const v4* __restrict__ C4,
    const v4* __restrict__ D4,
    v4* __restrict__ O4)
{
    const unsigned t = blockIdx.x * blockDim.x + threadIdx.x;   // 0 .. 524287
    const unsigned col = t & (NC4 - 1);                          // float4 column
    const unsigned rowBase = (t >> 11) * ROWS_PER_THREAD;        // t / 2048 * 32

    const v4 d = D4[col];                    // loaded once, register-resident

    const v4* __restrict__ cp = C4 + (size_t)rowBase * NC4 + col;
    v4* __restrict__ op       = O4 + (size_t)rowBase * NC4 + col;

#pragma unroll 8
    for (int r = 0; r < ROWS_PER_THREAD; ++r) {
        v4 c = __builtin_nontemporal_load(cp + (size_t)r * NC4);
        __builtin_nontemporal_store(c * d, op + (size_t)r * NC4);
    }
}

extern "C" void kernel_launch(void* const* d_in, const int* in_sizes, int n_in,
                              void* d_out, int out_size, void* d_ws, size_t ws_size,
                              hipStream_t stream) {
    const v4* C4 = (const v4*)d_in[0];
    const v4* D4 = (const v4*)d_in[1];
    v4* O4 = (v4*)d_out;

    colscale_kernel<<<BLOCKS, THREADS, 0, stream>>>(C4, D4, O4);
}